// Round 1
// baseline (2465.242 us; speedup 1.0000x reference)
//
#include <hip/hip_runtime.h>
#include <math.h>

#define RADIUS 3
#define T_STEPS 2
#define TASKS 4
#define IN_ATOM 39
#define IN_BOND 10
#define FD 256
#define Bm 128
#define Lm 128
#define Dm 6
#define NBONDSm 256
#define NEGV -9e8f
#define NROWS (Bm*Lm)   /* 16384 */

__device__ __forceinline__ float lrelu(float x){ return x > 0.f ? x : 0.01f*x; }
__device__ __forceinline__ float eluf(float x){ return x > 0.f ? x : expm1f(x); }
__device__ __forceinline__ float sigm(float x){ return 1.f/(1.f+expf(-x)); }

__device__ __forceinline__ float block_reduce_sum(float v, float* red){
  #pragma unroll
  for(int o=32;o>0;o>>=1) v += __shfl_down(v,o,64);
  __syncthreads();                      // protect red[] from previous use
  if((threadIdx.x&63)==0) red[threadIdx.x>>6]=v;
  __syncthreads();
  return red[0]+red[1]+red[2]+red[3];
}

__device__ __forceinline__ float block_reduce_max(float v, float* red){
  #pragma unroll
  for(int o=32;o>0;o>>=1) v = fmaxf(v, __shfl_down(v,o,64));
  __syncthreads();
  if((threadIdx.x&63)==0) red[threadIdx.x>>6]=v;
  __syncthreads();
  return fmaxf(fmaxf(red[0],red[1]),fmaxf(red[2],red[3]));
}

// WT[mat][k][n] = W[mat][n][k];  W is count x N x K contiguous
__global__ void k_transpose(const float* __restrict__ W, float* __restrict__ WT, int N, int K){
  int mat = blockIdx.y;
  int idx = blockIdx.x*256 + threadIdx.x;
  if(idx < N*K){
    int n = idx / K, k = idx - n*K;
    WT[(size_t)mat*N*K + (size_t)k*N + n] = W[(size_t)mat*N*K + idx];
  }
}

// atom_feature = lrelu(atom_list @ atom_fc_w.T + b); atom_proj = atom_list @ nfc_w[:, :39].T
__global__ __launch_bounds__(256) void k_atomfc(
  const float* __restrict__ atom_list, const float* __restrict__ afc_w,
  const float* __restrict__ afc_b, const float* __restrict__ nfc_w,
  float* __restrict__ atom_feature, float* __restrict__ atom_proj){
  __shared__ float Al[16][IN_ATOM];
  int m0 = blockIdx.x*16, t = threadIdx.x;
  for(int i=t;i<16*IN_ATOM;i+=256)
    Al[i/IN_ATOM][i%IN_ATOM] = atom_list[(size_t)(m0 + i/IN_ATOM)*IN_ATOM + i%IN_ATOM];
  __syncthreads();
  float accA[16], accP[16];
  #pragma unroll
  for(int m=0;m<16;m++){accA[m]=0.f;accP[m]=0.f;}
  for(int k=0;k<IN_ATOM;k++){
    float wa = afc_w[t*IN_ATOM+k];
    float wn = nfc_w[t*(IN_ATOM+IN_BOND)+k];
    #pragma unroll
    for(int m=0;m<16;m++){ float a=Al[m][k]; accA[m]+=a*wa; accP[m]+=a*wn; }
  }
  float bb = afc_b[t];
  #pragma unroll
  for(int m=0;m<16;m++){
    atom_feature[(size_t)(m0+m)*FD+t] = lrelu(accA[m]+bb);
    atom_proj[(size_t)(m0+m)*FD+t]    = accP[m];
  }
}

// bond_proj = bond_list @ nfc_w[:, 39:49].T + nfc_b   (bias folded here, once)
__global__ __launch_bounds__(256) void k_bondproj(
  const float* __restrict__ bond_list, const float* __restrict__ nfc_w,
  const float* __restrict__ nfc_b, float* __restrict__ bond_proj){
  __shared__ float Bl[16][IN_BOND];
  int m0 = blockIdx.x*16, t=threadIdx.x;
  for(int i=t;i<16*IN_BOND;i+=256)
    Bl[i/IN_BOND][i%IN_BOND] = bond_list[(size_t)(m0+i/IN_BOND)*IN_BOND + i%IN_BOND];
  __syncthreads();
  float acc[16];
  #pragma unroll
  for(int m=0;m<16;m++) acc[m]=0.f;
  for(int k=0;k<IN_BOND;k++){
    float wn = nfc_w[t*(IN_ATOM+IN_BOND)+IN_ATOM+k];
    #pragma unroll
    for(int m=0;m<16;m++) acc[m]+=Bl[m][k]*wn;
  }
  float bb=nfc_b[t];
  #pragma unroll
  for(int m=0;m<16;m++) bond_proj[(size_t)(m0+m)*FD+t]=acc[m]+bb;
}

// radius-0 attention: nbr feature built on the fly from atom_proj/bond_proj gathers
__global__ __launch_bounds__(256) void k_attn0(
  const float* __restrict__ atom_feature, const float* __restrict__ atom_proj,
  const float* __restrict__ bond_proj, const int* __restrict__ adeg,
  const int* __restrict__ bdeg, const float* __restrict__ align_w, /* 512, r=0 slice */
  const float* __restrict__ align_b, float* __restrict__ cpre, float* __restrict__ wsum){
  __shared__ float red[4];
  int row = blockIdx.x; int b = row >> 7; int t = threadIdx.x;
  float s_self = block_reduce_sum(align_w[t]*atom_feature[(size_t)row*FD+t], red);
  int ia[Dm]; float nbrv[Dm]; float s_n[Dm];
  #pragma unroll
  for(int d=0;d<Dm;d++){
    ia[d] = adeg[row*Dm+d];
    int ib = bdeg[row*Dm+d];
    float nf = atom_proj[(size_t)(b*Lm+ia[d])*FD+t] + bond_proj[(size_t)(b*NBONDSm+ib)*FD+t];
    nf = lrelu(nf);
    nbrv[d]=nf;
    s_n[d] = block_reduce_sum(align_w[FD+t]*nf, red);
  }
  float ab = align_b[0];
  float mx=-1e30f; float sc[Dm];
  #pragma unroll
  for(int d=0;d<Dm;d++){
    sc[d]=lrelu(s_self+s_n[d]+ab) + (ia[d]==Lm-1 ? NEGV : 0.f);
    mx = fmaxf(mx, sc[d]);
  }
  float se=0.f, ex[Dm];
  #pragma unroll
  for(int d=0;d<Dm;d++){ ex[d]=expf(sc[d]-mx); se+=ex[d]; }
  float inv=1.f/se, ws=0.f, cp=0.f;
  #pragma unroll
  for(int d=0;d<Dm;d++){
    float wd = ex[d]*inv * (ia[d]==Lm-1?0.f:1.f);
    ws+=wd; cp+=wd*nbrv[d];
  }
  cpre[(size_t)row*FD+t]=cp;
  if(t==0) wsum[row]=ws;
}

// per-row dots with align_w[r] (self half + nbr half), from `activated`
__global__ __launch_bounds__(256) void k_dots(
  const float* __restrict__ act, const float* __restrict__ w512,
  float* __restrict__ sself, float* __restrict__ snbr){
  __shared__ float red[4];
  int row=blockIdx.x; int t=threadIdx.x;
  float a = act[(size_t)row*FD+t];
  float s1 = block_reduce_sum(a*w512[t], red);
  float s2 = block_reduce_sum(a*w512[FD+t], red);
  if(t==0){ sself[row]=s1; snbr[row]=s2; }
}

// radius>=1 attention: scalar scores gathered, weighted sum of gathered activated rows
__global__ __launch_bounds__(256) void k_attnr(
  const float* __restrict__ activated, const float* __restrict__ sself,
  const float* __restrict__ snbr, const int* __restrict__ adeg,
  const float* __restrict__ align_b, float* __restrict__ cpre, float* __restrict__ wsum){
  int row=blockIdx.x; int b=row>>7; int t=threadIdx.x;
  float ss = sself[row]; float ab=align_b[0];
  int ia[Dm]; float sc[Dm]; float mx=-1e30f;
  #pragma unroll
  for(int d=0;d<Dm;d++){
    ia[d]=adeg[row*Dm+d];
    sc[d]=lrelu(ss+snbr[b*Lm+ia[d]]+ab)+(ia[d]==Lm-1?NEGV:0.f);
    mx=fmaxf(mx,sc[d]);
  }
  float se=0.f, ex[Dm];
  #pragma unroll
  for(int d=0;d<Dm;d++){ ex[d]=expf(sc[d]-mx); se+=ex[d]; }
  float inv=1.f/se, ws=0.f, wd[Dm];
  #pragma unroll
  for(int d=0;d<Dm;d++){ wd[d]=ex[d]*inv*(ia[d]==Lm-1?0.f:1.f); ws+=wd[d]; }
  float cp=0.f;
  #pragma unroll
  for(int d=0;d<Dm;d++) cp += wd[d]*activated[(size_t)(b*Lm+ia[d])*FD+t];
  cpre[(size_t)row*FD+t]=cp;
  if(t==0) wsum[row]=ws;
}

// C[M,256] = epi( A[M,256] @ Bt[256,256] ... ). epi: 2 = elu(acc + wsum[row]*bias), 3 = acc + bias
__global__ __launch_bounds__(256) void k_gemm256(
  const float* __restrict__ A, const float* __restrict__ Bt,
  const float* __restrict__ bias, const float* __restrict__ wsum,
  float* __restrict__ C, int epi){
  int m0=blockIdx.x*16, t=threadIdx.x;
  float acc[16];
  #pragma unroll
  for(int m=0;m<16;m++)acc[m]=0.f;
  const float* Arow = A + (size_t)m0*FD;
  for(int k=0;k<FD;k++){
    float bv = Bt[k*FD+t];
    #pragma unroll
    for(int m=0;m<16;m++) acc[m]+=Arow[m*FD+k]*bv;   // A loads are block-uniform -> scalar
  }
  float bb = bias[t];
  #pragma unroll
  for(int m=0;m<16;m++){
    float v=acc[m];
    if(epi==2)      v = eluf(v + wsum[m0+m]*bb);
    else            v = v + bb;
    C[(size_t)(m0+m)*FD+t]=v;
  }
}

// fused GRU: gi = X@WihT + bih ; gh = H@WhhT + bhh ; gates; Hout (may alias Hprev), Act=relu, Snap
__global__ __launch_bounds__(256) void k_gru(
  const float* __restrict__ X, const float* __restrict__ Hprev,
  const float* __restrict__ WihT, const float* __restrict__ WhhT,
  const float* __restrict__ bih, const float* __restrict__ bhh,
  float* __restrict__ Hout, float* __restrict__ Act, float* __restrict__ Snap){
  const int TM=16;
  int m0=blockIdx.x*TM, t=threadIdx.x;
  float gi[TM][3], gh[TM][3];
  #pragma unroll
  for(int m=0;m<TM;m++){gi[m][0]=gi[m][1]=gi[m][2]=0.f; gh[m][0]=gh[m][1]=gh[m][2]=0.f;}
  const float* Xr = X + (size_t)m0*FD;
  const float* Hr = Hprev + (size_t)m0*FD;
  for(int k=0;k<FD;k++){
    float wi0=WihT[k*768+t], wi1=WihT[k*768+256+t], wi2=WihT[k*768+512+t];
    float wh0=WhhT[k*768+t], wh1=WhhT[k*768+256+t], wh2=WhhT[k*768+512+t];
    #pragma unroll
    for(int m=0;m<TM;m++){
      float x=Xr[m*FD+k], h=Hr[m*FD+k];      // block-uniform -> scalar loads
      gi[m][0]+=x*wi0; gi[m][1]+=x*wi1; gi[m][2]+=x*wi2;
      gh[m][0]+=h*wh0; gh[m][1]+=h*wh1; gh[m][2]+=h*wh2;
    }
  }
  float b0=bih[t],b1=bih[256+t],b2=bih[512+t];
  float c0=bhh[t],c1=bhh[256+t],c2=bhh[512+t];
  float hnew[TM];
  #pragma unroll
  for(int m=0;m<TM;m++){
    float hp = Hr[(size_t)m*FD+t];
    float r = sigm(gi[m][0]+b0 + gh[m][0]+c0);
    float z = sigm(gi[m][1]+b1 + gh[m][1]+c1);
    float n = tanhf(gi[m][2]+b2 + r*(gh[m][2]+c2));
    hnew[m] = (1.f-z)*n + z*hp;
  }
  __syncthreads();   // all reads of Hprev done before any in-place write
  #pragma unroll
  for(int m=0;m<TM;m++){
    Hout[(size_t)(m0+m)*FD+t]=hnew[m];
    float a=fmaxf(hnew[m],0.f);
    if(Act)  Act[(size_t)(m0+m)*FD+t]=a;
    if(Snap) Snap[(size_t)(m0+m)*FD+t]=a;
  }
}

// mol_feature[b] = sum_l activated*mask ; act_mol = relu
__global__ __launch_bounds__(256) void k_molfeat(
  const float* __restrict__ act, const float* __restrict__ amask,
  float* __restrict__ molf, float* __restrict__ actmol){
  int b=blockIdx.x, t=threadIdx.x;
  float s=0.f;
  for(int l=0;l<Lm;l++) s += act[(size_t)(b*Lm+l)*FD+t]*amask[b*Lm+l];
  molf[b*FD+t]=s; actmol[b*FD+t]=fmaxf(s,0.f);
}

// per-task dots of activated with mol_align_w[i][0][256:512]
__global__ __launch_bounds__(256) void k_sact2(
  const float* __restrict__ act, const float* __restrict__ mol_align_w,
  float* __restrict__ sact2){
  __shared__ float red[4];
  int row=blockIdx.x; int t=threadIdx.x;
  float a = act[(size_t)row*FD+t];
  for(int i=0;i<TASKS;i++){
    float s = block_reduce_sum(a*mol_align_w[i*2*FD + FD + t], red);
    if(t==0) sact2[(size_t)i*NROWS+row]=s;
  }
}

// one mol-attention step for task `task`: softmax over L, weighted sum of act_t, elu
__global__ __launch_bounds__(256) void k_molattn(
  const float* __restrict__ actmol, const float* __restrict__ sact2,
  const float* __restrict__ mol_align_w, const float* __restrict__ mol_align_b,
  int task, const float* __restrict__ amask, const float* __restrict__ act_t,
  float* __restrict__ molctx){
  __shared__ float red[4]; __shared__ float wl[Lm];
  int b=blockIdx.x, t=threadIdx.x;
  const float* wm = mol_align_w + task*2*FD;
  float sm = block_reduce_sum(wm[t]*actmol[b*FD+t], red);
  float mb = mol_align_b[task];
  float sc = -1e30f;
  if(t<Lm){
    float am = amask[b*Lm+t];
    sc = lrelu(sm + sact2[(size_t)task*NROWS + b*Lm + t] + mb) + (am==0.f?NEGV:0.f);
  }
  float mx = block_reduce_max(sc, red);
  float e = (t<Lm)? expf(sc-mx) : 0.f;
  float se = block_reduce_sum(e, red);
  if(t<Lm) wl[t] = e/se * amask[b*Lm+t];
  __syncthreads();
  float acc=0.f;
  for(int l=0;l<Lm;l++) acc += wl[l]*act_t[(size_t)(b*Lm+l)*FD+t];
  molctx[b*FD+t]=eluf(acc);
}

extern "C" void kernel_launch(void* const* d_in, const int* in_sizes, int n_in,
                              void* d_out, int out_size, void* d_ws, size_t ws_size,
                              hipStream_t stream) {
  (void)in_sizes; (void)n_in; (void)out_size; (void)ws_size;
  const float* atom_list   = (const float*)d_in[0];
  const float* bond_list   = (const float*)d_in[1];
  const int*   adeg        = (const int*)d_in[2];
  const int*   bdeg        = (const int*)d_in[3];
  const float* amask       = (const float*)d_in[4];
  const float* atom_fc_w   = (const float*)d_in[5];
  const float* atom_fc_b   = (const float*)d_in[6];
  const float* nfc_w       = (const float*)d_in[7];
  const float* nfc_b       = (const float*)d_in[8];
  const float* align_w     = (const float*)d_in[9];   // [3,1,512]
  const float* align_b     = (const float*)d_in[10];  // [3,1]
  const float* attend_w    = (const float*)d_in[11];  // [3,256,256]
  const float* attend_b    = (const float*)d_in[12];  // [3,256]
  const float* gru_wih     = (const float*)d_in[13];  // [3,768,256]
  const float* gru_whh     = (const float*)d_in[14];
  const float* gru_bih     = (const float*)d_in[15];  // [3,768]
  const float* gru_bhh     = (const float*)d_in[16];
  const float* mgru_wih    = (const float*)d_in[17];  // [768,256]
  const float* mgru_whh    = (const float*)d_in[18];
  const float* mgru_bih    = (const float*)d_in[19];
  const float* mgru_bhh    = (const float*)d_in[20];
  const float* mol_align_w = (const float*)d_in[21];  // [4,1,512]
  const float* mol_align_b = (const float*)d_in[22];  // [4,1]
  const float* mol_att_w   = (const float*)d_in[23];  // [256,256]
  const float* mol_att_b   = (const float*)d_in[24];
  float* out = (float*)d_out;

  float* ws = (float*)d_ws;
  size_t o=0;
  float* wt_att  = ws+o; o += (size_t)3*FD*FD;
  float* wt_wih  = ws+o; o += (size_t)3*FD*768;
  float* wt_whh  = ws+o; o += (size_t)3*FD*768;
  float* wt_mwih = ws+o; o += (size_t)FD*768;
  float* wt_mwhh = ws+o; o += (size_t)FD*768;
  float* wt_matt = ws+o; o += (size_t)FD*FD;
  float* AF   = ws+o; o += (size_t)NROWS*FD;          // atom_feature
  float* AP   = ws+o; o += (size_t)NROWS*FD;          // atom_proj -> ctx -> act_t
  float* BP   = ws+o; o += (size_t)Bm*NBONDSm*FD;     // bond_proj -> {H, ACT}
  float* CPRE = ws+o; o += (size_t)NROWS*FD;
  float* WSUM = ws+o; o += NROWS;
  float* SSELF= ws+o; o += NROWS;
  float* SNBR = ws+o; o += NROWS;
  float* SACT2= ws+o; o += (size_t)TASKS*NROWS;
  float* MOLF = ws+o; o += Bm*FD;
  float* ACTM = ws+o; o += Bm*FD;
  float* MCTX = ws+o; o += Bm*FD;
  float* H   = BP;                  // bond_proj dead after attn0
  float* ACT = BP + (size_t)NROWS*FD;

  dim3 tb(256);
  // weight transposes (Bt layout [K,N] for coalesced GEMM reads)
  k_transpose<<<dim3((FD*FD+255)/256, 3), tb, 0, stream>>>(attend_w, wt_att, FD, FD);
  k_transpose<<<dim3((768*FD+255)/256, 3), tb, 0, stream>>>(gru_wih, wt_wih, 768, FD);
  k_transpose<<<dim3((768*FD+255)/256, 3), tb, 0, stream>>>(gru_whh, wt_whh, 768, FD);
  k_transpose<<<dim3((768*FD+255)/256, 1), tb, 0, stream>>>(mgru_wih, wt_mwih, 768, FD);
  k_transpose<<<dim3((768*FD+255)/256, 1), tb, 0, stream>>>(mgru_whh, wt_mwhh, 768, FD);
  k_transpose<<<dim3((FD*FD+255)/256, 1), tb, 0, stream>>>(mol_att_w, wt_matt, FD, FD);

  k_atomfc<<<NROWS/16, tb, 0, stream>>>(atom_list, atom_fc_w, atom_fc_b, nfc_w, AF, AP);
  k_bondproj<<<Bm*NBONDSm/16, tb, 0, stream>>>(bond_list, nfc_w, nfc_b, BP);

  // radius 0
  k_attn0<<<NROWS, tb, 0, stream>>>(AF, AP, BP, adeg, bdeg, align_w, align_b, CPRE, WSUM);
  k_gemm256<<<NROWS/16, tb, 0, stream>>>(CPRE, wt_att, attend_b, WSUM, AP, 2);
  k_gru<<<NROWS/16, tb, 0, stream>>>(AP, AF, wt_wih, wt_whh, gru_bih, gru_bhh, H, ACT, nullptr);

  // radius 1..2
  for(int r=1;r<RADIUS;r++){
    k_dots<<<NROWS, tb, 0, stream>>>(ACT, align_w + r*2*FD, SSELF, SNBR);
    k_attnr<<<NROWS, tb, 0, stream>>>(ACT, SSELF, SNBR, adeg, align_b + r, CPRE, WSUM);
    k_gemm256<<<NROWS/16, tb, 0, stream>>>(CPRE, wt_att + (size_t)r*FD*FD, attend_b + r*FD, WSUM, AP, 2);
    k_gru<<<NROWS/16, tb, 0, stream>>>(AP, H, wt_wih + (size_t)r*FD*768, wt_whh + (size_t)r*FD*768,
                                       gru_bih + r*768, gru_bhh + r*768, H, ACT, nullptr);
  }

  // molecule phase
  k_molfeat<<<Bm, tb, 0, stream>>>(ACT, amask, MOLF, ACTM);
  k_gemm256<<<NROWS/16, tb, 0, stream>>>(ACT, wt_matt, mol_att_b, nullptr, AP, 3); // act_t -> AP
  k_sact2<<<NROWS, tb, 0, stream>>>(ACT, mol_align_w, SACT2);

  for(int i=0;i<TASKS;i++){
    for(int tt=0;tt<T_STEPS;tt++){
      k_molattn<<<Bm, tb, 0, stream>>>(ACTM, SACT2, mol_align_w, mol_align_b, i, amask, AP, MCTX);
      float* snap = (tt==T_STEPS-1) ? (out + (size_t)i*Bm*FD) : nullptr;
      k_gru<<<Bm/16, tb, 0, stream>>>(MCTX, MOLF, wt_mwih, wt_mwhh, mgru_bih, mgru_bhh,
                                      MOLF, ACTM, snap);
    }
  }
}

// Round 2
// 1306.136 us; speedup vs baseline: 1.8874x; 1.8874x over previous
//
#include <hip/hip_runtime.h>
#include <math.h>

#define RADIUS 3
#define T_STEPS 2
#define TASKS 4
#define IN_ATOM 39
#define IN_BOND 10
#define FD 256
#define Bm 128
#define Lm 128
#define Dm 6
#define NBONDSm 256
#define NEGV -9e8f
#define NROWS (Bm*Lm)   /* 16384 */

__device__ __forceinline__ float lrelu(float x){ return x > 0.f ? x : 0.01f*x; }
__device__ __forceinline__ float eluf(float x){ return x > 0.f ? x : expm1f(x); }
__device__ __forceinline__ float sigm(float x){ return 1.f/(1.f+expf(-x)); }
__device__ __forceinline__ float dot4(float4 a, float4 b){
  return a.x*b.x + a.y*b.y + a.z*b.z + a.w*b.w;
}
__device__ __forceinline__ float4 lrelu4(float4 v){
  return make_float4(lrelu(v.x),lrelu(v.y),lrelu(v.z),lrelu(v.w));
}
__device__ __forceinline__ float wred(float v){
  #pragma unroll
  for(int o=32;o>0;o>>=1) v += __shfl_xor(v,o,64);
  return v;
}
__device__ __forceinline__ float bsum512(float v, float* red){
  #pragma unroll
  for(int o=32;o>0;o>>=1) v += __shfl_xor(v,o,64);
  __syncthreads();
  if((threadIdx.x&63)==0) red[threadIdx.x>>6]=v;
  __syncthreads();
  float s=0.f;
  #pragma unroll
  for(int i=0;i<8;i++) s+=red[i];
  return s;
}
__device__ __forceinline__ float bmax512(float v, float* red){
  #pragma unroll
  for(int o=32;o>0;o>>=1) v = fmaxf(v,__shfl_xor(v,o,64));
  __syncthreads();
  if((threadIdx.x&63)==0) red[threadIdx.x>>6]=v;
  __syncthreads();
  float s=-1e30f;
  #pragma unroll
  for(int i=0;i<8;i++) s=fmaxf(s,red[i]);
  return s;
}

// pack W[n][k] (K=256) -> WP[k/4][N][4]: float4 at (kg*N + n) holds W[n][4kg..4kg+3]
__global__ void k_pack4(const float* __restrict__ W, float* __restrict__ WP, int N){
  int mat = blockIdx.y;
  int idx = blockIdx.x*256 + threadIdx.x;
  if(idx < N*256){
    int n = idx >> 8, k = idx & 255;
    WP[(size_t)mat*N*256 + (size_t)(k>>2)*N*4 + n*4 + (k&3)] = W[(size_t)mat*N*256 + idx];
  }
}

// atom_feature = lrelu(atom_list @ atom_fc_w.T + b); atom_proj = atom_list @ nfc_w[:, :39].T
__global__ __launch_bounds__(256) void k_atomfc(
  const float* __restrict__ atom_list, const float* __restrict__ afc_w,
  const float* __restrict__ afc_b, const float* __restrict__ nfc_w,
  float* __restrict__ atom_feature, float* __restrict__ atom_proj){
  __shared__ float Al[16][IN_ATOM];
  int m0 = blockIdx.x*16, t = threadIdx.x;
  for(int i=t;i<16*IN_ATOM;i+=256)
    Al[i/IN_ATOM][i%IN_ATOM] = atom_list[(size_t)(m0 + i/IN_ATOM)*IN_ATOM + i%IN_ATOM];
  __syncthreads();
  float accA[16], accP[16];
  #pragma unroll
  for(int m=0;m<16;m++){accA[m]=0.f;accP[m]=0.f;}
  for(int k=0;k<IN_ATOM;k++){
    float wa = afc_w[t*IN_ATOM+k];
    float wn = nfc_w[t*(IN_ATOM+IN_BOND)+k];
    #pragma unroll
    for(int m=0;m<16;m++){ float a=Al[m][k]; accA[m]+=a*wa; accP[m]+=a*wn; }
  }
  float bb = afc_b[t];
  #pragma unroll
  for(int m=0;m<16;m++){
    atom_feature[(size_t)(m0+m)*FD+t] = lrelu(accA[m]+bb);
    atom_proj[(size_t)(m0+m)*FD+t]    = accP[m];
  }
}

// bond_proj = bond_list @ nfc_w[:, 39:49].T + nfc_b
__global__ __launch_bounds__(256) void k_bondproj(
  const float* __restrict__ bond_list, const float* __restrict__ nfc_w,
  const float* __restrict__ nfc_b, float* __restrict__ bond_proj){
  __shared__ float Bl[16][IN_BOND];
  int m0 = blockIdx.x*16, t=threadIdx.x;
  for(int i=t;i<16*IN_BOND;i+=256)
    Bl[i/IN_BOND][i%IN_BOND] = bond_list[(size_t)(m0+i/IN_BOND)*IN_BOND + i%IN_BOND];
  __syncthreads();
  float acc[16];
  #pragma unroll
  for(int m=0;m<16;m++) acc[m]=0.f;
  for(int k=0;k<IN_BOND;k++){
    float wn = nfc_w[t*(IN_ATOM+IN_BOND)+IN_ATOM+k];
    #pragma unroll
    for(int m=0;m<16;m++) acc[m]+=Bl[m][k]*wn;
  }
  float bb=nfc_b[t];
  #pragma unroll
  for(int m=0;m<16;m++) bond_proj[(size_t)(m0+m)*FD+t]=acc[m]+bb;
}

// radius-0 attention, wave-per-row (4 rows/block). lane owns features lane*4..lane*4+3
__global__ __launch_bounds__(256) void k_attn0(
  const float* __restrict__ AF, const float* __restrict__ APj,
  const float* __restrict__ BP, const int* __restrict__ adeg,
  const int* __restrict__ bdeg, const float* __restrict__ align_w,
  const float* __restrict__ align_b, float* __restrict__ cpre, float* __restrict__ wsum){
  int wid = threadIdx.x>>6, lane = threadIdx.x&63;
  int row = blockIdx.x*4 + wid; int b = row >> 7;
  float4 af = *(const float4*)&AF[(size_t)row*FD + lane*4];
  float4 w1 = *(const float4*)&align_w[lane*4];
  float4 w2 = *(const float4*)&align_w[FD + lane*4];
  float s_self = wred(dot4(af,w1));
  int ia[Dm]; float4 nbr[Dm]; float s_n[Dm];
  #pragma unroll
  for(int d=0;d<Dm;d++){
    ia[d] = adeg[row*Dm+d];
    int ib = bdeg[row*Dm+d];
    float4 ap = *(const float4*)&APj[(size_t)(b*Lm+ia[d])*FD + lane*4];
    float4 bp = *(const float4*)&BP[(size_t)(b*NBONDSm+ib)*FD + lane*4];
    float4 nf = lrelu4(make_float4(ap.x+bp.x,ap.y+bp.y,ap.z+bp.z,ap.w+bp.w));
    nbr[d]=nf;
    s_n[d] = wred(dot4(nf,w2));
  }
  float ab = align_b[0];
  float mx=-1e30f; float sc[Dm];
  #pragma unroll
  for(int d=0;d<Dm;d++){
    sc[d]=lrelu(s_self+s_n[d]+ab) + (ia[d]==Lm-1 ? NEGV : 0.f);
    mx = fmaxf(mx, sc[d]);
  }
  float se=0.f, ex[Dm];
  #pragma unroll
  for(int d=0;d<Dm;d++){ ex[d]=expf(sc[d]-mx); se+=ex[d]; }
  float inv=1.f/se, ws=0.f;
  float4 cp = make_float4(0,0,0,0);
  #pragma unroll
  for(int d=0;d<Dm;d++){
    float wd = ex[d]*inv * (ia[d]==Lm-1?0.f:1.f);
    ws+=wd;
    cp.x+=wd*nbr[d].x; cp.y+=wd*nbr[d].y; cp.z+=wd*nbr[d].z; cp.w+=wd*nbr[d].w;
  }
  *(float4*)&cpre[(size_t)row*FD + lane*4] = cp;
  if(lane==0) wsum[row]=ws;
}

// per-row dots with align_w[r], wave-per-row
__global__ __launch_bounds__(256) void k_dots(
  const float* __restrict__ act, const float* __restrict__ w512,
  float* __restrict__ sself, float* __restrict__ snbr){
  int wid=threadIdx.x>>6, lane=threadIdx.x&63;
  int row=blockIdx.x*4+wid;
  float4 aq = *(const float4*)&act[(size_t)row*FD + lane*4];
  float4 w1 = *(const float4*)&w512[lane*4];
  float4 w2 = *(const float4*)&w512[FD + lane*4];
  float s1 = wred(dot4(aq,w1));
  float s2 = wred(dot4(aq,w2));
  if(lane==0){ sself[row]=s1; snbr[row]=s2; }
}

// radius>=1 attention, wave-per-row
__global__ __launch_bounds__(256) void k_attnr(
  const float* __restrict__ activated, const float* __restrict__ sself,
  const float* __restrict__ snbr, const int* __restrict__ adeg,
  const float* __restrict__ align_b, float* __restrict__ cpre, float* __restrict__ wsum){
  int wid=threadIdx.x>>6, lane=threadIdx.x&63;
  int row=blockIdx.x*4+wid; int b=row>>7;
  float ss = sself[row]; float ab=align_b[0];
  int ia[Dm]; float sc[Dm]; float mx=-1e30f;
  #pragma unroll
  for(int d=0;d<Dm;d++){
    ia[d]=adeg[row*Dm+d];
    sc[d]=lrelu(ss+snbr[b*Lm+ia[d]]+ab)+(ia[d]==Lm-1?NEGV:0.f);
    mx=fmaxf(mx,sc[d]);
  }
  float se=0.f, ex[Dm];
  #pragma unroll
  for(int d=0;d<Dm;d++){ ex[d]=expf(sc[d]-mx); se+=ex[d]; }
  float inv=1.f/se, ws=0.f, wd[Dm];
  #pragma unroll
  for(int d=0;d<Dm;d++){ wd[d]=ex[d]*inv*(ia[d]==Lm-1?0.f:1.f); ws+=wd[d]; }
  float4 cp = make_float4(0,0,0,0);
  #pragma unroll
  for(int d=0;d<Dm;d++){
    float4 av = *(const float4*)&activated[(size_t)(b*Lm+ia[d])*FD + lane*4];
    cp.x+=wd[d]*av.x; cp.y+=wd[d]*av.y; cp.z+=wd[d]*av.z; cp.w+=wd[d]*av.w;
  }
  *(float4*)&cpre[(size_t)row*FD + lane*4] = cp;
  if(lane==0) wsum[row]=ws;
}

// C[M,256] = epi( A[M,256] @ W.T ), W packed [k/4][256][4]. 32 rows/block, 2 cols/thread.
// epi: 2 = elu(acc + wsum[row]*bias), 3 = acc + bias
__global__ __launch_bounds__(256) void k_gemm256(
  const float* __restrict__ A, const float* __restrict__ WP,
  const float* __restrict__ bias, const float* __restrict__ wsum,
  float* __restrict__ C, int epi){
  __shared__ __align__(16) float SA[32][FD];
  int m0=blockIdx.x*32;
  int tc = threadIdx.x & 127;      // column pair: tc, tc+128
  int rg = threadIdx.x >> 7;       // row group of 16
  {
    const float4* A4 = (const float4*)(A + (size_t)m0*FD);
    float4* S4 = (float4*)&SA[0][0];
    for(int i=threadIdx.x;i<32*FD/4;i+=256) S4[i]=A4[i];
  }
  __syncthreads();
  float acc[16][2];
  #pragma unroll
  for(int m=0;m<16;m++){acc[m][0]=0.f;acc[m][1]=0.f;}
  const float4* W4 = (const float4*)WP;
  for(int kg=0;kg<FD/4;kg++){
    float4 b0 = W4[kg*FD + tc];
    float4 b1 = W4[kg*FD + tc+128];
    #pragma unroll
    for(int m=0;m<16;m++){
      float4 aq = *(const float4*)&SA[rg*16+m][kg*4];
      acc[m][0] += dot4(aq,b0);
      acc[m][1] += dot4(aq,b1);
    }
  }
  float bb0 = bias[tc], bb1 = bias[tc+128];
  #pragma unroll
  for(int m=0;m<16;m++){
    int row = m0 + rg*16 + m;
    float v0=acc[m][0], v1=acc[m][1];
    if(epi==2){ float w=wsum[row]; v0=eluf(v0+w*bb0); v1=eluf(v1+w*bb1); }
    else      { v0+=bb0; v1+=bb1; }
    C[(size_t)row*FD+tc]=v0;
    C[(size_t)row*FD+tc+128]=v1;
  }
}

// fused GRU: 512 threads, 16 rows/block (2 groups x 8 rows). Weights packed [k/4][768][4].
__global__ __launch_bounds__(512) void k_gru2(
  const float* __restrict__ X, const float* __restrict__ Hprev,
  const float* __restrict__ WihP, const float* __restrict__ WhhP,
  const float* __restrict__ bih, const float* __restrict__ bhh,
  float* __restrict__ Hout, float* __restrict__ Act){
  __shared__ __align__(16) float SX[16][FD];
  __shared__ __align__(16) float SH[16][FD];
  int m0 = blockIdx.x*16;
  int t  = threadIdx.x & 255;
  int g  = threadIdx.x >> 8;
  {
    const float4* X4 = (const float4*)(X + (size_t)m0*FD);
    const float4* H4 = (const float4*)(Hprev + (size_t)m0*FD);
    float4* SX4=(float4*)&SX[0][0];
    float4* SH4=(float4*)&SH[0][0];
    for(int i=threadIdx.x;i<16*FD/4;i+=512){ SX4[i]=X4[i]; SH4[i]=H4[i]; }
  }
  __syncthreads();
  float acc[8][6];
  #pragma unroll
  for(int m=0;m<8;m++)
    #pragma unroll
    for(int j=0;j<6;j++) acc[m][j]=0.f;
  const int rbase = g*8;
  const float4* WI = (const float4*)WihP;
  const float4* WH = (const float4*)WhhP;
  for(int kg=0;kg<FD/4;kg++){
    float4 wi0 = WI[kg*768 + t];
    float4 wi1 = WI[kg*768 + 256 + t];
    float4 wi2 = WI[kg*768 + 512 + t];
    float4 wh0 = WH[kg*768 + t];
    float4 wh1 = WH[kg*768 + 256 + t];
    float4 wh2 = WH[kg*768 + 512 + t];
    #pragma unroll
    for(int m=0;m<8;m++){
      float4 xq = *(const float4*)&SX[rbase+m][kg*4];
      float4 hq = *(const float4*)&SH[rbase+m][kg*4];
      acc[m][0] += dot4(xq,wi0);
      acc[m][1] += dot4(xq,wi1);
      acc[m][2] += dot4(xq,wi2);
      acc[m][3] += dot4(hq,wh0);
      acc[m][4] += dot4(hq,wh1);
      acc[m][5] += dot4(hq,wh2);
    }
  }
  float b0=bih[t],b1=bih[256+t],b2=bih[512+t];
  float c0=bhh[t],c1=bhh[256+t],c2=bhh[512+t];
  #pragma unroll
  for(int m=0;m<8;m++){
    int row = m0 + rbase + m;
    float hp = SH[rbase+m][t];
    float r = sigm(acc[m][0]+b0 + acc[m][3]+c0);
    float z = sigm(acc[m][1]+b1 + acc[m][4]+c1);
    float n = tanhf(acc[m][2]+b2 + r*(acc[m][5]+c2));
    float hn = (1.f-z)*n + z*hp;
    Hout[(size_t)row*FD+t]=hn;
    Act[(size_t)row*FD+t]=fmaxf(hn,0.f);
  }
}

// per-task dots of activated with mol_align_w[i][0][256:512], wave-per-row
__global__ __launch_bounds__(256) void k_sact2(
  const float* __restrict__ act, const float* __restrict__ mol_align_w,
  float* __restrict__ sact2){
  int wid=threadIdx.x>>6, lane=threadIdx.x&63;
  int row=blockIdx.x*4+wid;
  float4 aq = *(const float4*)&act[(size_t)row*FD + lane*4];
  #pragma unroll
  for(int i=0;i<TASKS;i++){
    float4 wq = *(const float4*)&mol_align_w[i*2*FD + FD + lane*4];
    float s = wred(dot4(aq,wq));
    if(lane==0) sact2[(size_t)i*NROWS+row]=s;
  }
}

// fused mol phase: one block per molecule, 512 threads, all TASKS x T_STEPS inside.
__global__ __launch_bounds__(512) void k_molphase(
  const float* __restrict__ ACT, const float* __restrict__ amask,
  const float* __restrict__ sact2, const float* __restrict__ mol_align_w,
  const float* __restrict__ mol_align_b, const float* __restrict__ act_t,
  const float* __restrict__ WihP, const float* __restrict__ WhhP,
  const float* __restrict__ bih, const float* __restrict__ bhh,
  float* __restrict__ out){
  __shared__ __align__(16) float HS[FD];
  __shared__ __align__(16) float XS[FD];
  __shared__ float ACTM[FD];
  __shared__ float GH[3*FD];
  __shared__ float WL[Lm];
  __shared__ float red[8];
  int b = blockIdx.x;
  int t = threadIdx.x;        // 0..511
  int tg = t & 255;
  // mol_feature = sum_l ACT*mask
  if(t<FD){
    float s=0.f;
    for(int l=0;l<Lm;l++) s += ACT[(size_t)(b*Lm+l)*FD+t]*amask[b*Lm+l];
    HS[t]=s; ACTM[t]=fmaxf(s,0.f);
  }
  __syncthreads();
  const float4* WI = (const float4*)WihP;
  const float4* WH = (const float4*)WhhP;
  for(int task=0;task<TASKS;task++){
    const float* MW = mol_align_w + task*2*FD;
    float mb = mol_align_b[task];
    for(int tt=0;tt<T_STEPS;tt++){
      // score self-dot
      float pv = (t<FD)? MW[t]*ACTM[t] : 0.f;
      float sm = bsum512(pv, red);
      float sc = -1e30f;
      if(t<Lm){
        float am = amask[b*Lm+t];
        sc = lrelu(sm + sact2[(size_t)task*NROWS + b*Lm + t] + mb) + (am==0.f?NEGV:0.f);
      }
      float mx = bmax512(sc, red);
      float e = (t<Lm)? expf(sc-mx) : 0.f;
      float se = bsum512(e, red);
      if(t<Lm) WL[t] = e/se*amask[b*Lm+t];
      __syncthreads();
      if(t<FD){
        float a0=0.f;
        for(int l=0;l<Lm;l++) a0 += WL[l]*act_t[(size_t)(b*Lm+l)*FD+t];
        XS[t]=eluf(a0);
      }
      __syncthreads();
      // GRU: group A (t<256) computes gi for col t from XS; group B computes gh from HS
      float g0=0.f,g1=0.f,g2=0.f;
      if(t<FD){
        const float4* S4=(const float4*)XS;
        for(int kg=0;kg<FD/4;kg++){
          float4 xq = S4[kg];
          g0 += dot4(xq, WI[kg*768 + tg]);
          g1 += dot4(xq, WI[kg*768 + 256 + tg]);
          g2 += dot4(xq, WI[kg*768 + 512 + tg]);
        }
      } else {
        const float4* S4=(const float4*)HS;
        for(int kg=0;kg<FD/4;kg++){
          float4 hq = S4[kg];
          g0 += dot4(hq, WH[kg*768 + tg]);
          g1 += dot4(hq, WH[kg*768 + 256 + tg]);
          g2 += dot4(hq, WH[kg*768 + 512 + tg]);
        }
        GH[tg]=g0; GH[256+tg]=g1; GH[512+tg]=g2;
      }
      __syncthreads();
      if(t<FD){
        float hp = HS[t];
        float r = sigm(g0+bih[t] + GH[t]+bhh[t]);
        float z = sigm(g1+bih[256+t] + GH[256+t]+bhh[256+t]);
        float n = tanhf(g2+bih[512+t] + r*(GH[512+t]+bhh[512+t]));
        float hn = (1.f-z)*n + z*hp;
        HS[t]=hn;
        float am = fmaxf(hn,0.f);
        ACTM[t]=am;
        if(tt==T_STEPS-1) out[((size_t)task*Bm + b)*FD + t]=am;
      }
      __syncthreads();
    }
  }
}

extern "C" void kernel_launch(void* const* d_in, const int* in_sizes, int n_in,
                              void* d_out, int out_size, void* d_ws, size_t ws_size,
                              hipStream_t stream) {
  (void)in_sizes; (void)n_in; (void)out_size; (void)ws_size;
  const float* atom_list   = (const float*)d_in[0];
  const float* bond_list   = (const float*)d_in[1];
  const int*   adeg        = (const int*)d_in[2];
  const int*   bdeg        = (const int*)d_in[3];
  const float* amask       = (const float*)d_in[4];
  const float* atom_fc_w   = (const float*)d_in[5];
  const float* atom_fc_b   = (const float*)d_in[6];
  const float* nfc_w       = (const float*)d_in[7];
  const float* nfc_b       = (const float*)d_in[8];
  const float* align_w     = (const float*)d_in[9];   // [3,1,512]
  const float* align_b     = (const float*)d_in[10];  // [3,1]
  const float* attend_w    = (const float*)d_in[11];  // [3,256,256]
  const float* attend_b    = (const float*)d_in[12];  // [3,256]
  const float* gru_wih     = (const float*)d_in[13];  // [3,768,256]
  const float* gru_whh     = (const float*)d_in[14];
  const float* gru_bih     = (const float*)d_in[15];  // [3,768]
  const float* gru_bhh     = (const float*)d_in[16];
  const float* mgru_wih    = (const float*)d_in[17];  // [768,256]
  const float* mgru_whh    = (const float*)d_in[18];
  const float* mgru_bih    = (const float*)d_in[19];
  const float* mgru_bhh    = (const float*)d_in[20];
  const float* mol_align_w = (const float*)d_in[21];  // [4,1,512]
  const float* mol_align_b = (const float*)d_in[22];  // [4,1]
  const float* mol_att_w   = (const float*)d_in[23];  // [256,256]
  const float* mol_att_b   = (const float*)d_in[24];
  float* out = (float*)d_out;

  float* ws = (float*)d_ws;
  size_t o=0;
  float* wp_att  = ws+o; o += (size_t)3*FD*FD;
  float* wp_wih  = ws+o; o += (size_t)3*FD*768;
  float* wp_whh  = ws+o; o += (size_t)3*FD*768;
  float* wp_mwih = ws+o; o += (size_t)FD*768;
  float* wp_mwhh = ws+o; o += (size_t)FD*768;
  float* wp_matt = ws+o; o += (size_t)FD*FD;
  float* AF   = ws+o; o += (size_t)NROWS*FD;          // atom_feature
  float* AP   = ws+o; o += (size_t)NROWS*FD;          // atom_proj -> ctx -> act_t
  float* BP   = ws+o; o += (size_t)Bm*NBONDSm*FD;     // bond_proj -> {H, ACT}
  float* CPRE = ws+o; o += (size_t)NROWS*FD;
  float* WSUM = ws+o; o += NROWS;
  float* SSELF= ws+o; o += NROWS;
  float* SNBR = ws+o; o += NROWS;
  float* SACT2= ws+o; o += (size_t)TASKS*NROWS;
  float* H   = BP;                  // bond_proj dead after attn0
  float* ACT = BP + (size_t)NROWS*FD;

  dim3 tb(256);
  k_pack4<<<dim3(256,3), tb, 0, stream>>>(attend_w, wp_att, FD);
  k_pack4<<<dim3(768,3), tb, 0, stream>>>(gru_wih, wp_wih, 768);
  k_pack4<<<dim3(768,3), tb, 0, stream>>>(gru_whh, wp_whh, 768);
  k_pack4<<<dim3(768,1), tb, 0, stream>>>(mgru_wih, wp_mwih, 768);
  k_pack4<<<dim3(768,1), tb, 0, stream>>>(mgru_whh, wp_mwhh, 768);
  k_pack4<<<dim3(256,1), tb, 0, stream>>>(mol_att_w, wp_matt, FD);

  k_atomfc<<<NROWS/16, tb, 0, stream>>>(atom_list, atom_fc_w, atom_fc_b, nfc_w, AF, AP);
  k_bondproj<<<Bm*NBONDSm/16, tb, 0, stream>>>(bond_list, nfc_w, nfc_b, BP);

  // radius 0
  k_attn0<<<NROWS/4, tb, 0, stream>>>(AF, AP, BP, adeg, bdeg, align_w, align_b, CPRE, WSUM);
  k_gemm256<<<NROWS/32, tb, 0, stream>>>(CPRE, wp_att, attend_b, WSUM, AP, 2);
  k_gru2<<<NROWS/16, dim3(512), 0, stream>>>(AP, AF, wp_wih, wp_whh, gru_bih, gru_bhh, H, ACT);

  // radius 1..2
  for(int r=1;r<RADIUS;r++){
    k_dots<<<NROWS/4, tb, 0, stream>>>(ACT, align_w + r*2*FD, SSELF, SNBR);
    k_attnr<<<NROWS/4, tb, 0, stream>>>(ACT, SSELF, SNBR, adeg, align_b + r, CPRE, WSUM);
    k_gemm256<<<NROWS/32, tb, 0, stream>>>(CPRE, wp_att + (size_t)r*FD*FD, attend_b + r*FD, WSUM, AP, 2);
    k_gru2<<<NROWS/16, dim3(512), 0, stream>>>(AP, H, wp_wih + (size_t)r*FD*768, wp_whh + (size_t)r*FD*768,
                                               gru_bih + r*768, gru_bhh + r*768, H, ACT);
  }

  // molecule phase
  k_gemm256<<<NROWS/32, tb, 0, stream>>>(ACT, wp_matt, mol_att_b, nullptr, AP, 3); // act_t
  k_sact2<<<NROWS/4, tb, 0, stream>>>(ACT, mol_align_w, SACT2);
  k_molphase<<<Bm, dim3(512), 0, stream>>>(ACT, amask, SACT2, mol_align_w, mol_align_b,
                                           AP, wp_mwih, wp_mwhh, mgru_bih, mgru_bhh, out);
}